// Round 13
// baseline (389.846 us; speedup 1.0000x reference)
//
#include <hip/hip_runtime.h>

#define NN 50000
#define EE 400000
#define FF 128
#define NRBF 20
#define MAXDEG 64
#define PI_OVER_CUT 0.6283185307179586f   // pi / 5.0

typedef _Float16 h8 __attribute__((ext_vector_type(8)));
typedef float    f4 __attribute__((ext_vector_type(4)));
typedef unsigned int u4 __attribute__((ext_vector_type(4)));

union pk32 { unsigned int u; _Float16 h[2]; };

// ---------------------------------------------------------------------------
// Convert all GEMM weights to f16 once; also zeroes counts.
__global__ __launch_bounds__(256) void k_wconv(
    const float* __restrict__ Wu, const float* __restrict__ Wv,
    const float* __restrict__ Wu1, const float* __restrict__ Wu2,
    const float* __restrict__ Wp1, const float* __restrict__ Wp2,
    const float* __restrict__ Ww, const float* __restrict__ bw,
    _Float16* __restrict__ Wuh, _Float16* __restrict__ Wvh,
    _Float16* __restrict__ Wu1h, _Float16* __restrict__ Wu2h,
    _Float16* __restrict__ Wp1h, _Float16* __restrict__ Wp2h,
    _Float16* __restrict__ Wwh32, int* __restrict__ counts)
{
    int i = blockIdx.x * 256 + threadIdx.x;
    if (i < NN) counts[i] = 0;
    if (i < 16384) { Wuh[i] = (_Float16)Wu[i]; Wvh[i] = (_Float16)Wv[i];
                     Wp1h[i] = (_Float16)Wp1[i]; }
    if (i < 32768) { Wu1h[i] = (_Float16)Wu1[i]; }
    if (i < 49152) { Wu2h[i] = (_Float16)Wu2[i]; Wp2h[i] = (_Float16)Wp2[i]; }
    if (i < 8192) {
        int col = i >> 5, k = i & 31;
        int sr = col < 128 ? col : col + 128;
        _Float16 v = (_Float16)0.f;
        if (k < 20)       v = (_Float16)Ww[sr * NRBF + k];
        else if (k == 20) v = (_Float16)bw[sr];
        Wwh32[i] = v;
    }
}

// ---------------------------------------------------------------------------
// K1 (merged): edge bucketing + node MLP (unchanged).
__global__ __launch_bounds__(256) void k_phi_bucket(
    const float* __restrict__ emb, const int* __restrict__ z,
    const _Float16* __restrict__ Wp1h, const float* __restrict__ bp1,
    const _Float16* __restrict__ Wp2h, const float* __restrict__ bp2,
    unsigned int* __restrict__ phi_pk, _Float16* __restrict__ s_h,
    const int* __restrict__ dst, int* __restrict__ counts,
    int* __restrict__ slots)
{
    __shared__ _Float16 Ss[32 * 128];
    __shared__ _Float16 H1s[32 * 128];

    const int t    = threadIdx.x;
    const int lane = t & 63;
    const int w    = t >> 6;
    const int lr   = lane & 15;
    const int lq   = lane >> 4;
    const int n0   = blockIdx.x * 32;
    const f4 z4 = {0.f, 0.f, 0.f, 0.f};

    // ---- bucket prologue (atomics overlap the staging below) ----
    {
        int e = blockIdx.x * 256 + t;
        if (e < EE) {
            int n = dst[e];
            int slot = atomicAdd(&counts[n], 1);
            if (slot < MAXDEG) slots[n * MAXDEG + slot] = e;
        }
    }

    for (int i = t; i < 512; i += 256) {             // 32 rows x 16 granules
        int n = i >> 4, gr = i & 15;
        int nn = n0 + n; if (nn > NN - 1) nn = NN - 1;
        const float* sp = &emb[(size_t)z[nn] * FF + gr * 8];
        float4 aa = *(const float4*)sp;
        float4 bb = *(const float4*)(sp + 4);
        h8 hv;
        hv[0] = (_Float16)aa.x; hv[1] = (_Float16)aa.y;
        hv[2] = (_Float16)aa.z; hv[3] = (_Float16)aa.w;
        hv[4] = (_Float16)bb.x; hv[5] = (_Float16)bb.y;
        hv[6] = (_Float16)bb.z; hv[7] = (_Float16)bb.w;
        *(h8*)&Ss[(n * 16 + (gr ^ (n & 15))) * 8] = hv;
        *(h8*)&s_h[(size_t)nn * FF + gr * 8] = hv;
    }
    __syncthreads();

    f4 acc1[2][2];
    #pragma unroll
    for (int a = 0; a < 2; ++a)
        #pragma unroll
        for (int m = 0; m < 2; ++m) acc1[a][m] = z4;
    {
        const _Float16* bb = Wp1h + (size_t)lr * 128 + lq * 8;
        #pragma unroll
        for (int g2 = 0; g2 < 2; ++g2) {
            h8 bf[4];
            #pragma unroll
            for (int ks = 0; ks < 4; ++ks)
                bf[ks] = *(const h8*)(bb + ((2 * w + g2) * 16) * 128 + ks * 32);
            #pragma unroll
            for (int mt = 0; mt < 2; ++mt) {
                const int r = mt * 16 + lr;
                #pragma unroll
                for (int ks = 0; ks < 4; ++ks) {
                    h8 af = *(const h8*)&Ss[(r * 16 + ((ks * 4 + lq) ^ (r & 15))) * 8];
                    acc1[g2][mt] = __builtin_amdgcn_mfma_f32_16x16x32_f16(
                        af, bf[ks], acc1[g2][mt], 0, 0, 0);
                }
            }
        }
    }
    #pragma unroll
    for (int g2 = 0; g2 < 2; ++g2) {
        const int g = (2 * w + g2) * 16 + lr;
        const float b1 = bp1[g];
        #pragma unroll
        for (int mt = 0; mt < 2; ++mt)
            #pragma unroll
            for (int r = 0; r < 4; ++r) {
                float x = acc1[g2][mt][r] + b1;
                float y = x / (1.f + __expf(-x));
                int n = mt * 16 + lq * 4 + r;
                H1s[(n * 16 + ((g >> 3) ^ (n & 15))) * 8 + (g & 7)] = (_Float16)y;
            }
    }
    __syncthreads();

    f4 accS[2][2], accV[2][2];
    #pragma unroll
    for (int a = 0; a < 2; ++a)
        #pragma unroll
        for (int m = 0; m < 2; ++m) { accS[a][m] = z4; accV[a][m] = z4; }
    {
        const _Float16* bbs = Wp2h + (size_t)lr * 128 + lq * 8;
        const _Float16* bbv = Wp2h + (size_t)(256 + lr) * 128 + lq * 8;
        #pragma unroll
        for (int g2 = 0; g2 < 2; ++g2) {
            h8 bfs[4], bfv[4];
            #pragma unroll
            for (int ks = 0; ks < 4; ++ks) {
                bfs[ks] = *(const h8*)(bbs + ((2 * w + g2) * 16) * 128 + ks * 32);
                bfv[ks] = *(const h8*)(bbv + ((2 * w + g2) * 16) * 128 + ks * 32);
            }
            #pragma unroll
            for (int mt = 0; mt < 2; ++mt) {
                const int r = mt * 16 + lr;
                #pragma unroll
                for (int ks = 0; ks < 4; ++ks) {
                    h8 af = *(const h8*)&H1s[(r * 16 + ((ks * 4 + lq) ^ (r & 15))) * 8];
                    accS[g2][mt] = __builtin_amdgcn_mfma_f32_16x16x32_f16(
                        af, bfs[ks], accS[g2][mt], 0, 0, 0);
                    accV[g2][mt] = __builtin_amdgcn_mfma_f32_16x16x32_f16(
                        af, bfv[ks], accV[g2][mt], 0, 0, 0);
                }
            }
        }
    }
    #pragma unroll
    for (int g2 = 0; g2 < 2; ++g2) {
        const int g = (2 * w + g2) * 16 + lr;
        const float bsa = bp2[g], bva = bp2[256 + g];
        #pragma unroll
        for (int mt = 0; mt < 2; ++mt)
            #pragma unroll
            for (int r = 0; r < 4; ++r) {
                int n = mt * 16 + lq * 4 + r;
                int nn = n0 + n;
                if (nn < NN) {
                    pk32 pk;
                    pk.h[0] = (_Float16)(accS[g2][mt][r] + bsa);
                    pk.h[1] = (_Float16)(accV[g2][mt][r] + bva);
                    phi_pk[(size_t)nn * FF + g] = pk.u;
                }
            }
    }
}

// ---------------------------------------------------------------------------
// K2 (MFMA Wf): block-per-node, BARRIER-FREE (unchanged).
__global__ __launch_bounds__(128) void k_edge_mfma(
    const float* __restrict__ pos,
    const _Float16* __restrict__ Wwh32,
    const int* __restrict__ src,
    const int* __restrict__ counts, const int* __restrict__ slots,
    const unsigned int* __restrict__ phi_pk,
    _Float16* __restrict__ s_h,
    _Float16* __restrict__ xg)
{
    __shared__ _Float16 A[2][16 * 32];        // per-wave swizzled rbf tile (2 KB)
    __shared__ float dirs[2][16][4];          // per-wave ux,uy,uz,asfloat(sI)
    __shared__ unsigned int wfi[2][16 * 66];  // per-wave packed {s,v} Wf (8.25 KB)

    const int t    = threadIdx.x;
    const int lane = t & 63;
    const int w    = t >> 6;     // wave id: features [64w, 64w+64)
    const int lr   = lane & 15;
    const int lq   = lane >> 4;
    const int m    = lane & 15;  // edge slot this lane serves
    const int ks   = lane >> 4;  // k-slot group (0..3)
    const int n    = blockIdx.x;
    const f4 z4 = {0.f, 0.f, 0.f, 0.f};

    // B-fragments: js<4 -> s-gate cols 64w+16js; js>=4 -> v-gate (L2-hot).
    h8 bf[8];
    #pragma unroll
    for (int js = 0; js < 8; ++js) {
        int col = (js < 4) ? (w * 64 + js * 16 + lr)
                           : (128 + w * 64 + (js - 4) * 16 + lr);
        bf[js] = *(const h8*)&Wwh32[(size_t)col * 32 + lq * 8];
    }

    const float px = pos[3 * n], py = pos[3 * n + 1], pz = pos[3 * n + 2];

    int deg = counts[n];
    deg = deg > MAXDEG ? MAXDEG : deg;

    const int gf = w * 64 + lane;            // this thread's feature
    const size_t gi = (size_t)n * FF + gf;
    float s_old = (float)s_h[gi];            // issued early, used at the end

    float acc_s = 0.f, av0 = 0.f, av1 = 0.f, av2 = 0.f;

    for (int t0 = 0; t0 < deg; t0 += 16) {
        const int degT = (deg - t0) < 16 ? (deg - t0) : 16;
        // ---- geometry + rbf: 4 lanes per edge (broadcast loads) ----
        {
            int mc = (m < degT) ? m : 0;     // clamp to a valid edge
            int e  = slots[n * MAXDEG + t0 + mc];
            int sI = src[e];
            float rx = px - pos[3 * sI];
            float ry = py - pos[3 * sI + 1];
            float rz = pz - pos[3 * sI + 2];
            float d = sqrtf(rx * rx + ry * ry + rz * rz);
            d = fmaxf(d, 1e-9f);
            float di = 1.f / d;
            if (lane < 16) {
                dirs[w][lane][0] = rx * di;
                dirs[w][lane][1] = ry * di;
                dirs[w][lane][2] = rz * di;
                dirs[w][lane][3] = __int_as_float(sI);
            }
            // lane covers k = ks + 4j, j=0..7 (k = ks..ks+28)
            float vv[8];
            #pragma unroll
            for (int j = 0; j < 5; ++j)      // k = ks+4j <= 19 for ks<4
                vv[j] = __sinf((float)(ks + 4 * j + 1) * PI_OVER_CUT * d) * di;
            vv[5] = (ks == 0) ? 1.0f : 0.f;  // k = 20: bias element
            vv[6] = 0.f; vv[7] = 0.f;
            #pragma unroll
            for (int j = 0; j < 8; ++j) {
                int k = ks + 4 * j;
                A[w][m * 32 + (((k >> 3) ^ (m & 3)) * 8) + (k & 7)] = (_Float16)vv[j];
            }
        }
        // ---- MFMA: both gates for this wave's 64 features; pack to dwords ----
        {
            h8 af = *(const h8*)&A[w][(lr * 4 + (lq ^ (lr & 3))) * 8];
            #pragma unroll
            for (int js = 0; js < 4; ++js) {
                f4 dd_s = __builtin_amdgcn_mfma_f32_16x16x32_f16(af, bf[js],     z4, 0, 0, 0);
                f4 dd_v = __builtin_amdgcn_mfma_f32_16x16x32_f16(af, bf[js + 4], z4, 0, 0, 0);
                #pragma unroll
                for (int r = 0; r < 4; ++r) {
                    pk32 pk;
                    pk.h[0] = (_Float16)dd_s[r];
                    pk.h[1] = (_Float16)dd_v[r];
                    wfi[w][(lq * 4 + r) * 66 + js * 16 + lr] = pk.u;
                }
            }
        }
        // ---- batched 16-wide phi gathers, then FMA pass ----
        {
            unsigned int phr[16];
            #pragma unroll
            for (int mm = 0; mm < 16; ++mm) {
                int sim = __builtin_amdgcn_readfirstlane(
                              __float_as_int(dirs[w][mm][3]));
                phr[mm] = (mm < degT) ? phi_pk[(size_t)sim * FF + gf] : 0u;
            }
            #pragma unroll
            for (int mm = 0; mm < 16; ++mm) {
                if (mm < degT) {
                    pk32 ph, wfu;
                    ph.u  = phr[mm];
                    wfu.u = wfi[w][mm * 66 + lane];
                    float ps = (float)ph.h[0] * (float)wfu.h[0];
                    float pv = (float)ph.h[1] * (float)wfu.h[1];
                    acc_s += ps;
                    av0 = fmaf(pv, dirs[w][mm][0], av0);
                    av1 = fmaf(pv, dirs[w][mm][1], av1);
                    av2 = fmaf(pv, dirs[w][mm][2], av2);
                }
            }
        }
    }

    s_h[gi] = (_Float16)(s_old + acc_s);
    xg[((size_t)n * 3 + 0) * FF + gf] = (_Float16)av0;
    xg[((size_t)n * 3 + 1) * FF + gf] = (_Float16)av1;
    xg[((size_t)n * 3 + 2) * FF + gf] = (_Float16)av2;
}

// ---------------------------------------------------------------------------
// K3: update block, 16 nodes/block, 8 waves x 16 features (512 threads,
// high occupancy) + NON-TEMPORAL loads/stores via ext_vector types:
// outputs bypass L2 allocate (no write-thrash), read-once streams don't
// pollute. Tests the L2-write-allocate theory of R9/R10's phantom traffic.
__global__ __launch_bounds__(512, 8) void k_update_mfma(
    const _Float16* __restrict__ xg, const _Float16* __restrict__ s_h,
    const _Float16* __restrict__ Wuh, const _Float16* __restrict__ Wvh,
    const _Float16* __restrict__ Wu1h, const _Float16* __restrict__ Wu2h,
    const float* __restrict__ bu, const float* __restrict__ bv,
    const float* __restrict__ bu1, const float* __restrict__ bu2,
    float* __restrict__ s_io, float* __restrict__ v_io)
{
    __shared__ __align__(16) char smem[24576];
    _Float16* Xs  = (_Float16*)smem;            // 48*128 f16 (12 KB)
    _Float16* Hs  = (_Float16*)(smem + 12288);  // 16*256 f16 (8 KB)
    _Float16* H1s = (_Float16*)(smem + 20480);  // 16*128 f16 (4 KB)
    float*    vbuf = (float*)smem;              // 16*128*3 f32 overlay (24 KB)

    const int t    = threadIdx.x;
    const int lane = t & 63;
    const int w    = t >> 6;     // wave 0..7: features [16w, 16w+16)
    const int lr   = lane & 15;  // A-row / B-col within tile
    const int lq   = lane >> 4;  // k-chunk selector
    const int n0   = blockIdx.x * 16;           // NN % 16 == 0: no tail
    const f4 z4 = {0.f, 0.f, 0.f, 0.f};
    const int g    = w * 16 + lr;   // this lane's output feature

    // ---- stage Xs from xg (48 rows x 16 granules, nontemporal) ----
    for (int i = t; i < 768; i += 512) {
        int row = i >> 4, gr = i & 15;
        int n = row & 15;
        int c = row >> 4;
        int nn = n0 + n;
        u4 d = __builtin_nontemporal_load(
            (const u4*)&xg[((size_t)nn * 3 + c) * FF + gr * 8]);
        *(u4*)&Xs[(row * 16 + (gr ^ n)) * 8] = d;
    }
    // ---- stage s (f16, nontemporal) -> Hs[:, 0:128) ----
    if (t < 256) {
        int n = t >> 4, gr = t & 15;
        int nn = n0 + n;
        u4 d = __builtin_nontemporal_load(
            (const u4*)&s_h[(size_t)nn * FF + gr * 8]);
        *(u4*)&Hs[(n * 32 + (gr ^ n)) * 8] = d;
    }
    __syncthreads();

    // ---- GEMM1: U,V[c*16+n][g], wave owns 16 features ----
    f4 accU[3], accV[3];
    #pragma unroll
    for (int c = 0; c < 3; ++c) { accU[c] = z4; accV[c] = z4; }

    {   // U pass
        const _Float16* bb = Wuh + (size_t)g * 128 + lq * 8;
        h8 bfr[4];
        #pragma unroll
        for (int ks = 0; ks < 4; ++ks)
            bfr[ks] = *(const h8*)(bb + ks * 32);
        #pragma unroll
        for (int c = 0; c < 3; ++c) {
            const int rr = c * 16 + lr;
            #pragma unroll
            for (int ks = 0; ks < 4; ++ks) {
                h8 af = *(const h8*)&Xs[(rr * 16 + ((ks * 4 + lq) ^ lr)) * 8];
                accU[c] = __builtin_amdgcn_mfma_f32_16x16x32_f16(
                    af, bfr[ks], accU[c], 0, 0, 0);
            }
        }
    }
    {   // V pass
        const _Float16* bb = Wvh + (size_t)g * 128 + lq * 8;
        h8 bfr[4];
        #pragma unroll
        for (int ks = 0; ks < 4; ++ks)
            bfr[ks] = *(const h8*)(bb + ks * 32);
        #pragma unroll
        for (int c = 0; c < 3; ++c) {
            const int rr = c * 16 + lr;
            #pragma unroll
            for (int ks = 0; ks < 4; ++ks) {
                h8 af = *(const h8*)&Xs[(rr * 16 + ((ks * 4 + lq) ^ lr)) * 8];
                accV[c] = __builtin_amdgcn_mfma_f32_16x16x32_f16(
                    af, bfr[ks], accV[c], 0, 0, 0);
            }
        }
    }

    // ---- epilogue 1: bias, u.v, Vn -> Hs[:,128:256); pack U to f16 ----
    float uvr[4];
    unsigned int upk[3][2];
    {
        const float bU = bu[g], bV = bv[g];
        #pragma unroll
        for (int r = 0; r < 4; ++r) {
            float Ux = accU[0][r] + bU;
            float Uy = accU[1][r] + bU;
            float Uz = accU[2][r] + bU;
            float Vx = accV[0][r] + bV;
            float Vy = accV[1][r] + bV;
            float Vz = accV[2][r] + bV;
            accU[0][r] = Ux; accU[1][r] = Uy; accU[2][r] = Uz;
            uvr[r] = Ux * Vx + Uy * Vy + Uz * Vz;
            float vn = sqrtf(Vx * Vx + Vy * Vy + Vz * Vz);
            int n = lq * 4 + r;
            Hs[(n * 32 + ((16 + (g >> 3)) ^ n)) * 8 + (g & 7)] = (_Float16)vn;
        }
        #pragma unroll
        for (int c = 0; c < 3; ++c)
            #pragma unroll
            for (int rp = 0; rp < 2; ++rp) {
                pk32 p;
                p.h[0] = (_Float16)accU[c][2 * rp];
                p.h[1] = (_Float16)accU[c][2 * rp + 1];
                upk[c][rp] = p.u;
            }
    }
    __syncthreads();

    // ---- GEMM2: h1 = silu(Wu1 @ [s;Vn] + bu1), chunked B loads ----
    f4 acc2 = z4;
    {
        const _Float16* bb = Wu1h + (size_t)g * 256 + lq * 8;
        #pragma unroll
        for (int half = 0; half < 2; ++half) {
            h8 bfr[4];
            #pragma unroll
            for (int ks = 0; ks < 4; ++ks)
                bfr[ks] = *(const h8*)(bb + (half * 4 + ks) * 32);
            #pragma unroll
            for (int ks = 0; ks < 4; ++ks) {
                const int kk = half * 4 + ks;
                h8 af = *(const h8*)&Hs[(lr * 32 + ((kk * 4 + lq) ^ lr)) * 8];
                acc2 = __builtin_amdgcn_mfma_f32_16x16x32_f16(
                    af, bfr[ks], acc2, 0, 0, 0);
            }
        }
    }
    {
        const float b1 = bu1[g];
        #pragma unroll
        for (int r = 0; r < 4; ++r) {
            float x = acc2[r] + b1;
            float y = x / (1.f + __expf(-x));
            int n = lq * 4 + r;
            H1s[(n * 16 + ((g >> 3) ^ n)) * 8 + (g & 7)] = (_Float16)y;
        }
    }
    __syncthreads();

    // ---- GEMM3: a = Wu2 @ h1 + bu2, wave covers cols {g, 128+g, 256+g} ----
    f4 acc3[3];
    #pragma unroll
    for (int ai = 0; ai < 3; ++ai) {
        acc3[ai] = z4;
        const _Float16* bb = Wu2h + (size_t)(ai * 128 + g) * 128 + lq * 8;
        h8 bfr[4];
        #pragma unroll
        for (int ks = 0; ks < 4; ++ks)
            bfr[ks] = *(const h8*)(bb + ks * 32);
        #pragma unroll
        for (int ks = 0; ks < 4; ++ks) {
            h8 af = *(const h8*)&H1s[(lr * 16 + ((ks * 4 + lq) ^ lr)) * 8];
            acc3[ai] = __builtin_amdgcn_mfma_f32_16x16x32_f16(
                af, bfr[ks], acc3[ai], 0, 0, 0);
        }
    }

    // ---- epilogue 2: s -> global (nontemporal); v_new -> registers ----
    float vnew[3][4];
    {
        const float b1 = bu2[g], b2 = bu2[128 + g], b3 = bu2[256 + g];
        #pragma unroll
        for (int r = 0; r < 4; ++r) {
            int n = lq * 4 + r;
            int nn = n0 + n;
            float a1 = acc3[0][r] + b1;
            float a2 = acc3[1][r] + b2;
            float a3 = acc3[2][r] + b3;
            float s1 = (float)Hs[(n * 32 + ((g >> 3) ^ n)) * 8 + (g & 7)];
            __builtin_nontemporal_store(s1 + a2 + uvr[r] * a3,
                                        &s_io[(size_t)nn * FF + g]);
            pk32 p0, p1, p2;
            p0.u = upk[0][r >> 1];
            p1.u = upk[1][r >> 1];
            p2.u = upk[2][r >> 1];
            float Ux = (float)p0.h[r & 1];
            float Uy = (float)p1.h[r & 1];
            float Uz = (float)p2.h[r & 1];
            vnew[0][r] = (float)Xs[((0 * 16 + n) * 16 + ((g >> 3) ^ n)) * 8 + (g & 7)] + Ux * a1;
            vnew[1][r] = (float)Xs[((1 * 16 + n) * 16 + ((g >> 3) ^ n)) * 8 + (g & 7)] + Uy * a1;
            vnew[2][r] = (float)Xs[((2 * 16 + n) * 16 + ((g >> 3) ^ n)) * 8 + (g & 7)] + Uz * a1;
        }
    }
    __syncthreads();             // all waves done reading Xs/Hs/H1s

    // ---- overlay vbuf[n][f][c]; write contiguous nontemporal f4s ----
    #pragma unroll
    for (int r = 0; r < 4; ++r) {
        int n = lq * 4 + r;
        #pragma unroll
        for (int c = 0; c < 3; ++c)
            vbuf[n * 384 + g * 3 + c] = vnew[c][r];
    }
    __syncthreads();
    {
        float* vout = v_io + (size_t)n0 * 384;
        #pragma unroll
        for (int i = 0; i < 3; ++i) {
            int idx = t + i * 512;
            f4 d = *(f4*)&vbuf[idx * 4];
            __builtin_nontemporal_store(d, (f4*)&vout[idx * 4]);
        }
    }
}

// ---------------------------------------------------------------------------
extern "C" void kernel_launch(void* const* d_in, const int* in_sizes, int n_in,
                              void* d_out, int out_size, void* d_ws, size_t ws_size,
                              hipStream_t stream)
{
    const float* pos = (const float*)d_in[0];
    const float* emb = (const float*)d_in[1];
    const float* Wp1 = (const float*)d_in[2];
    const float* bp1 = (const float*)d_in[3];
    const float* Wp2 = (const float*)d_in[4];
    const float* bp2 = (const float*)d_in[5];
    const float* Ww  = (const float*)d_in[6];
    const float* bw  = (const float*)d_in[7];
    const float* Wu  = (const float*)d_in[8];
    const float* bu  = (const float*)d_in[9];
    const float* Wv  = (const float*)d_in[10];
    const float* bv  = (const float*)d_in[11];
    const float* Wu1 = (const float*)d_in[12];
    const float* bu1 = (const float*)d_in[13];
    const float* Wu2 = (const float*)d_in[14];
    const float* bu2 = (const float*)d_in[15];
    const int* z   = (const int*)d_in[16];
    const int* src = (const int*)d_in[17];
    const int* dst = (const int*)d_in[18];

    float* s_io = (float*)d_out;
    float* v_io = (float*)d_out + (size_t)NN * FF;

    char* ws = (char*)d_ws;
    unsigned int* phi_pk = (unsigned int*)ws;                 // NN*FF uints
    _Float16* xg    = (_Float16*)(phi_pk + (size_t)NN * FF);  // NN*3*FF
    _Float16* s_h   = xg + (size_t)NN * 3 * FF;               // NN*FF
    _Float16* Wuh   = s_h + (size_t)NN * FF;
    _Float16* Wvh   = Wuh  + 128 * 128;
    _Float16* Wu1h  = Wvh  + 128 * 128;
    _Float16* Wu2h  = Wu1h + 128 * 256;
    _Float16* Wp1h  = Wu2h + 384 * 128;
    _Float16* Wp2h  = Wp1h + 128 * 128;
    _Float16* Wwh32 = Wp2h + 384 * 128;                       // 256*32
    int* counts = (int*)(Wwh32 + 256 * 32);
    int* slots  = counts + NN;

    k_wconv <<<196, 256, 0, stream>>>(Wu, Wv, Wu1, Wu2, Wp1, Wp2, Ww, bw,
                                      Wuh, Wvh, Wu1h, Wu2h, Wp1h, Wp2h, Wwh32,
                                      counts);
    k_phi_bucket<<<(NN + 31) / 32, 256, 0, stream>>>(emb, z, Wp1h, bp1,
                                                     Wp2h, bp2, phi_pk, s_h,
                                                     dst, counts, slots);
    k_edge_mfma<<<NN, 128, 0, stream>>>(pos, Wwh32, src, counts, slots,
                                        phi_pk, s_h, xg);
    k_update_mfma<<<NN / 16, 512, 0, stream>>>(xg, s_h,
                                               Wuh, Wvh, Wu1h, Wu2h,
                                               bu, bv, bu1, bu2,
                                               s_io, v_io);
}

// Round 14
// 372.658 us; speedup vs baseline: 1.0461x; 1.0461x over previous
//
#include <hip/hip_runtime.h>

#define NN 50000
#define EE 400000
#define FF 128
#define NRBF 20
#define MAXDEG 64
#define PI_OVER_CUT 0.6283185307179586f   // pi / 5.0

typedef _Float16 h8 __attribute__((ext_vector_type(8)));
typedef float    f4 __attribute__((ext_vector_type(4)));

union pk32 { unsigned int u; _Float16 h[2]; };

// ---------------------------------------------------------------------------
// Convert all GEMM weights to f16 once; also zeroes counts.
__global__ __launch_bounds__(256) void k_wconv(
    const float* __restrict__ Wu, const float* __restrict__ Wv,
    const float* __restrict__ Wu1, const float* __restrict__ Wu2,
    const float* __restrict__ Wp1, const float* __restrict__ Wp2,
    const float* __restrict__ Ww, const float* __restrict__ bw,
    _Float16* __restrict__ Wuh, _Float16* __restrict__ Wvh,
    _Float16* __restrict__ Wu1h, _Float16* __restrict__ Wu2h,
    _Float16* __restrict__ Wp1h, _Float16* __restrict__ Wp2h,
    _Float16* __restrict__ Wwh32, int* __restrict__ counts)
{
    int i = blockIdx.x * 256 + threadIdx.x;
    if (i < NN) counts[i] = 0;
    if (i < 16384) { Wuh[i] = (_Float16)Wu[i]; Wvh[i] = (_Float16)Wv[i];
                     Wp1h[i] = (_Float16)Wp1[i]; }
    if (i < 32768) { Wu1h[i] = (_Float16)Wu1[i]; }
    if (i < 49152) { Wu2h[i] = (_Float16)Wu2[i]; Wp2h[i] = (_Float16)Wp2[i]; }
    if (i < 8192) {
        int col = i >> 5, k = i & 31;
        int sr = col < 128 ? col : col + 128;
        _Float16 v = (_Float16)0.f;
        if (k < 20)       v = (_Float16)Ww[sr * NRBF + k];
        else if (k == 20) v = (_Float16)bw[sr];
        Wwh32[i] = v;
    }
}

// ---------------------------------------------------------------------------
// K1 (merged): edge bucketing + node MLP (unchanged).
__global__ __launch_bounds__(256) void k_phi_bucket(
    const float* __restrict__ emb, const int* __restrict__ z,
    const _Float16* __restrict__ Wp1h, const float* __restrict__ bp1,
    const _Float16* __restrict__ Wp2h, const float* __restrict__ bp2,
    unsigned int* __restrict__ phi_pk, _Float16* __restrict__ s_h,
    const int* __restrict__ dst, int* __restrict__ counts,
    int* __restrict__ slots)
{
    __shared__ _Float16 Ss[32 * 128];
    __shared__ _Float16 H1s[32 * 128];

    const int t    = threadIdx.x;
    const int lane = t & 63;
    const int w    = t >> 6;
    const int lr   = lane & 15;
    const int lq   = lane >> 4;
    const int n0   = blockIdx.x * 32;
    const f4 z4 = {0.f, 0.f, 0.f, 0.f};

    // ---- bucket prologue (atomics overlap the staging below) ----
    {
        int e = blockIdx.x * 256 + t;
        if (e < EE) {
            int n = dst[e];
            int slot = atomicAdd(&counts[n], 1);
            if (slot < MAXDEG) slots[n * MAXDEG + slot] = e;
        }
    }

    for (int i = t; i < 512; i += 256) {             // 32 rows x 16 granules
        int n = i >> 4, gr = i & 15;
        int nn = n0 + n; if (nn > NN - 1) nn = NN - 1;
        const float* sp = &emb[(size_t)z[nn] * FF + gr * 8];
        float4 aa = *(const float4*)sp;
        float4 bb = *(const float4*)(sp + 4);
        h8 hv;
        hv[0] = (_Float16)aa.x; hv[1] = (_Float16)aa.y;
        hv[2] = (_Float16)aa.z; hv[3] = (_Float16)aa.w;
        hv[4] = (_Float16)bb.x; hv[5] = (_Float16)bb.y;
        hv[6] = (_Float16)bb.z; hv[7] = (_Float16)bb.w;
        *(h8*)&Ss[(n * 16 + (gr ^ (n & 15))) * 8] = hv;
        *(h8*)&s_h[(size_t)nn * FF + gr * 8] = hv;
    }
    __syncthreads();

    f4 acc1[2][2];
    #pragma unroll
    for (int a = 0; a < 2; ++a)
        #pragma unroll
        for (int m = 0; m < 2; ++m) acc1[a][m] = z4;
    {
        const _Float16* bb = Wp1h + (size_t)lr * 128 + lq * 8;
        #pragma unroll
        for (int g2 = 0; g2 < 2; ++g2) {
            h8 bf[4];
            #pragma unroll
            for (int ks = 0; ks < 4; ++ks)
                bf[ks] = *(const h8*)(bb + ((2 * w + g2) * 16) * 128 + ks * 32);
            #pragma unroll
            for (int mt = 0; mt < 2; ++mt) {
                const int r = mt * 16 + lr;
                #pragma unroll
                for (int ks = 0; ks < 4; ++ks) {
                    h8 af = *(const h8*)&Ss[(r * 16 + ((ks * 4 + lq) ^ (r & 15))) * 8];
                    acc1[g2][mt] = __builtin_amdgcn_mfma_f32_16x16x32_f16(
                        af, bf[ks], acc1[g2][mt], 0, 0, 0);
                }
            }
        }
    }
    #pragma unroll
    for (int g2 = 0; g2 < 2; ++g2) {
        const int g = (2 * w + g2) * 16 + lr;
        const float b1 = bp1[g];
        #pragma unroll
        for (int mt = 0; mt < 2; ++mt)
            #pragma unroll
            for (int r = 0; r < 4; ++r) {
                float x = acc1[g2][mt][r] + b1;
                float y = x / (1.f + __expf(-x));
                int n = mt * 16 + lq * 4 + r;
                H1s[(n * 16 + ((g >> 3) ^ (n & 15))) * 8 + (g & 7)] = (_Float16)y;
            }
    }
    __syncthreads();

    f4 accS[2][2], accV[2][2];
    #pragma unroll
    for (int a = 0; a < 2; ++a)
        #pragma unroll
        for (int m = 0; m < 2; ++m) { accS[a][m] = z4; accV[a][m] = z4; }
    {
        const _Float16* bbs = Wp2h + (size_t)lr * 128 + lq * 8;
        const _Float16* bbv = Wp2h + (size_t)(256 + lr) * 128 + lq * 8;
        #pragma unroll
        for (int g2 = 0; g2 < 2; ++g2) {
            h8 bfs[4], bfv[4];
            #pragma unroll
            for (int ks = 0; ks < 4; ++ks) {
                bfs[ks] = *(const h8*)(bbs + ((2 * w + g2) * 16) * 128 + ks * 32);
                bfv[ks] = *(const h8*)(bbv + ((2 * w + g2) * 16) * 128 + ks * 32);
            }
            #pragma unroll
            for (int mt = 0; mt < 2; ++mt) {
                const int r = mt * 16 + lr;
                #pragma unroll
                for (int ks = 0; ks < 4; ++ks) {
                    h8 af = *(const h8*)&H1s[(r * 16 + ((ks * 4 + lq) ^ (r & 15))) * 8];
                    accS[g2][mt] = __builtin_amdgcn_mfma_f32_16x16x32_f16(
                        af, bfs[ks], accS[g2][mt], 0, 0, 0);
                    accV[g2][mt] = __builtin_amdgcn_mfma_f32_16x16x32_f16(
                        af, bfv[ks], accV[g2][mt], 0, 0, 0);
                }
            }
        }
    }
    #pragma unroll
    for (int g2 = 0; g2 < 2; ++g2) {
        const int g = (2 * w + g2) * 16 + lr;
        const float bsa = bp2[g], bva = bp2[256 + g];
        #pragma unroll
        for (int mt = 0; mt < 2; ++mt)
            #pragma unroll
            for (int r = 0; r < 4; ++r) {
                int n = mt * 16 + lq * 4 + r;
                int nn = n0 + n;
                if (nn < NN) {
                    pk32 pk;
                    pk.h[0] = (_Float16)(accS[g2][mt][r] + bsa);
                    pk.h[1] = (_Float16)(accV[g2][mt][r] + bva);
                    phi_pk[(size_t)nn * FF + g] = pk.u;
                }
            }
    }
}

// ---------------------------------------------------------------------------
// K2 (MFMA Wf): block-per-node, BARRIER-FREE. Gather addresses now come
// from register broadcast (readlane of each lane's sI) instead of an LDS
// round-trip — shortens the per-edge address chain.
__global__ __launch_bounds__(128) void k_edge_mfma(
    const float* __restrict__ pos,
    const _Float16* __restrict__ Wwh32,
    const int* __restrict__ src,
    const int* __restrict__ counts, const int* __restrict__ slots,
    const unsigned int* __restrict__ phi_pk,
    _Float16* __restrict__ s_h,
    _Float16* __restrict__ xg)
{
    __shared__ _Float16 A[2][16 * 32];        // per-wave swizzled rbf tile (2 KB)
    __shared__ float dirs[2][16][4];          // per-wave ux,uy,uz (16B stride)
    __shared__ unsigned int wfi[2][16 * 66];  // per-wave packed {s,v} Wf (8.25 KB)

    const int t    = threadIdx.x;
    const int lane = t & 63;
    const int w    = t >> 6;     // wave id: features [64w, 64w+64)
    const int lr   = lane & 15;
    const int lq   = lane >> 4;
    const int m    = lane & 15;  // edge slot this lane serves
    const int ks   = lane >> 4;  // k-slot group (0..3)
    const int n    = blockIdx.x;
    const f4 z4 = {0.f, 0.f, 0.f, 0.f};

    // B-fragments: js<4 -> s-gate cols 64w+16js; js>=4 -> v-gate (L2-hot).
    h8 bf[8];
    #pragma unroll
    for (int js = 0; js < 8; ++js) {
        int col = (js < 4) ? (w * 64 + js * 16 + lr)
                           : (128 + w * 64 + (js - 4) * 16 + lr);
        bf[js] = *(const h8*)&Wwh32[(size_t)col * 32 + lq * 8];
    }

    const float px = pos[3 * n], py = pos[3 * n + 1], pz = pos[3 * n + 2];

    int deg = counts[n];
    deg = deg > MAXDEG ? MAXDEG : deg;

    const int gf = w * 64 + lane;            // this thread's feature
    const size_t gi = (size_t)n * FF + gf;
    float s_old = (float)s_h[gi];            // issued early, used at the end

    float acc_s = 0.f, av0 = 0.f, av1 = 0.f, av2 = 0.f;

    for (int t0 = 0; t0 < deg; t0 += 16) {
        const int degT = (deg - t0) < 16 ? (deg - t0) : 16;
        // ---- geometry + rbf: 4 lanes per edge (broadcast loads) ----
        int mc = (m < degT) ? m : 0;         // clamp to a valid edge
        int e  = slots[n * MAXDEG + t0 + mc];
        int sI = src[e];                     // stays register-resident
        {
            float rx = px - pos[3 * sI];
            float ry = py - pos[3 * sI + 1];
            float rz = pz - pos[3 * sI + 2];
            float d = sqrtf(rx * rx + ry * ry + rz * rz);
            d = fmaxf(d, 1e-9f);
            float di = 1.f / d;
            if (lane < 16) {
                dirs[w][lane][0] = rx * di;
                dirs[w][lane][1] = ry * di;
                dirs[w][lane][2] = rz * di;
            }
            // lane covers k = ks + 4j, j=0..7 (k = ks..ks+28)
            float vv[8];
            #pragma unroll
            for (int j = 0; j < 5; ++j)      // k = ks+4j <= 19 for ks<4
                vv[j] = __sinf((float)(ks + 4 * j + 1) * PI_OVER_CUT * d) * di;
            vv[5] = (ks == 0) ? 1.0f : 0.f;  // k = 20: bias element
            vv[6] = 0.f; vv[7] = 0.f;
            #pragma unroll
            for (int j = 0; j < 8; ++j) {
                int k = ks + 4 * j;
                A[w][m * 32 + (((k >> 3) ^ (m & 3)) * 8) + (k & 7)] = (_Float16)vv[j];
            }
        }
        // ---- MFMA: both gates for this wave's 64 features; pack to dwords ----
        {
            h8 af = *(const h8*)&A[w][(lr * 4 + (lq ^ (lr & 3))) * 8];
            #pragma unroll
            for (int js = 0; js < 4; ++js) {
                f4 dd_s = __builtin_amdgcn_mfma_f32_16x16x32_f16(af, bf[js],     z4, 0, 0, 0);
                f4 dd_v = __builtin_amdgcn_mfma_f32_16x16x32_f16(af, bf[js + 4], z4, 0, 0, 0);
                #pragma unroll
                for (int r = 0; r < 4; ++r) {
                    pk32 pk;
                    pk.h[0] = (_Float16)dd_s[r];
                    pk.h[1] = (_Float16)dd_v[r];
                    wfi[w][(lq * 4 + r) * 66 + js * 16 + lr] = pk.u;
                }
            }
        }
        // ---- batched 16-wide phi gathers (register-broadcast addresses) ----
        {
            unsigned int phr[16];
            #pragma unroll
            for (int mm = 0; mm < 16; ++mm) {
                int sim = __builtin_amdgcn_readlane(sI, mm);
                phr[mm] = (mm < degT) ? phi_pk[(size_t)sim * FF + gf] : 0u;
            }
            #pragma unroll
            for (int mm = 0; mm < 16; ++mm) {
                if (mm < degT) {
                    pk32 ph, wfu;
                    ph.u  = phr[mm];
                    wfu.u = wfi[w][mm * 66 + lane];
                    float ps = (float)ph.h[0] * (float)wfu.h[0];
                    float pv = (float)ph.h[1] * (float)wfu.h[1];
                    acc_s += ps;
                    av0 = fmaf(pv, dirs[w][mm][0], av0);
                    av1 = fmaf(pv, dirs[w][mm][1], av1);
                    av2 = fmaf(pv, dirs[w][mm][2], av2);
                }
            }
        }
    }

    s_h[gi] = (_Float16)(s_old + acc_s);
    xg[((size_t)n * 3 + 0) * FF + gf] = (_Float16)av0;
    xg[((size_t)n * 3 + 1) * FF + gf] = (_Float16)av1;
    xg[((size_t)n * 3 + 2) * FF + gf] = (_Float16)av2;
}

// ---------------------------------------------------------------------------
// K3: update block on f16 MFMA, 16 nodes/block, 4 waves x 32 features
// (R8/R11-measured optimum: 108 us, FETCH/WRITE ~= logical traffic).
// High-occupancy variants (R9/R10/R13) all generated ~+100 MB phantom DRAM
// traffic and ran ~10% slower — do not raise occupancy on this kernel.
__global__ __launch_bounds__(256) void k_update_mfma(
    const _Float16* __restrict__ xg, const _Float16* __restrict__ s_h,
    const _Float16* __restrict__ Wuh, const _Float16* __restrict__ Wvh,
    const _Float16* __restrict__ Wu1h, const _Float16* __restrict__ Wu2h,
    const float* __restrict__ bu, const float* __restrict__ bv,
    const float* __restrict__ bu1, const float* __restrict__ bu2,
    float* __restrict__ s_io, float* __restrict__ v_io)
{
    __shared__ _Float16 Xs[48 * 128];    // A for GEMM1: row = c*16+n, k = f (12 KB)
    __shared__ _Float16 Hs[16 * 256];    // A for GEMM2: [s | Vn]          (8 KB)
    __shared__ _Float16 H1s[16 * 128];   // A for GEMM3                    (4 KB)

    const int t    = threadIdx.x;
    const int lane = t & 63;
    const int w    = t >> 6;     // wave 0..3
    const int lr   = lane & 15;  // A-row / B-col within tile
    const int lq   = lane >> 4;  // k-chunk selector
    const int n0   = blockIdx.x * 16;
    const f4 z4 = {0.f, 0.f, 0.f, 0.f};

    // ---- stage Xs from xg (48 rows x 16 granules) ----
    for (int i = t; i < 768; i += 256) {
        int row = i >> 4, gr = i & 15;
        int n = row & 15, c = row >> 4;
        int nn = n0 + n; if (nn > NN - 1) nn = NN - 1;
        uint4 d = *(const uint4*)&xg[((size_t)nn * 3 + c) * FF + gr * 8];
        *(uint4*)&Xs[(row * 16 + (gr ^ n)) * 8] = d;
    }
    // ---- stage s (f16 direct) -> Hs[:, 0:128) : 16 rows x 16 granules ----
    {
        int n = t >> 4, gr = t & 15;
        int nn = n0 + n; if (nn > NN - 1) nn = NN - 1;
        uint4 d = *(const uint4*)&s_h[(size_t)nn * FF + gr * 8];
        *(uint4*)&Hs[(n * 32 + (gr ^ n)) * 8] = d;
    }
    __syncthreads();

    // ---- GEMM1: U,V[c*16+n][g] ----
    f4 accU[2][3], accV[2][3];   // [g-subtile][c]
    #pragma unroll
    for (int a = 0; a < 2; ++a)
        #pragma unroll
        for (int c = 0; c < 3; ++c) { accU[a][c] = z4; accV[a][c] = z4; }

    {   // U pass
        const _Float16* bb = Wuh + (size_t)lr * 128 + lq * 8;
        h8 bfr[2][4];
        #pragma unroll
        for (int g2 = 0; g2 < 2; ++g2)
            #pragma unroll
            for (int ks = 0; ks < 4; ++ks)
                bfr[g2][ks] = *(const h8*)(bb + ((2 * w + g2) * 16) * 128 + ks * 32);
        #pragma unroll
        for (int c = 0; c < 3; ++c) {
            const int rr = c * 16 + lr;
            h8 af[4];
            #pragma unroll
            for (int ks = 0; ks < 4; ++ks)
                af[ks] = *(const h8*)&Xs[(rr * 16 + ((ks * 4 + lq) ^ lr)) * 8];
            #pragma unroll
            for (int g2 = 0; g2 < 2; ++g2)
                #pragma unroll
                for (int ks = 0; ks < 4; ++ks)
                    accU[g2][c] = __builtin_amdgcn_mfma_f32_16x16x32_f16(
                        af[ks], bfr[g2][ks], accU[g2][c], 0, 0, 0);
        }
    }
    {   // V pass
        const _Float16* bb = Wvh + (size_t)lr * 128 + lq * 8;
        h8 bfr[2][4];
        #pragma unroll
        for (int g2 = 0; g2 < 2; ++g2)
            #pragma unroll
            for (int ks = 0; ks < 4; ++ks)
                bfr[g2][ks] = *(const h8*)(bb + ((2 * w + g2) * 16) * 128 + ks * 32);
        #pragma unroll
        for (int c = 0; c < 3; ++c) {
            const int rr = c * 16 + lr;
            h8 af[4];
            #pragma unroll
            for (int ks = 0; ks < 4; ++ks)
                af[ks] = *(const h8*)&Xs[(rr * 16 + ((ks * 4 + lq) ^ lr)) * 8];
            #pragma unroll
            for (int g2 = 0; g2 < 2; ++g2)
                #pragma unroll
                for (int ks = 0; ks < 4; ++ks)
                    accV[g2][c] = __builtin_amdgcn_mfma_f32_16x16x32_f16(
                        af[ks], bfr[g2][ks], accV[g2][c], 0, 0, 0);
        }
    }

    // ---- epilogue 1: bias, u.v, Vn -> Hs[:,128:256) ----
    float uvr[2][4];
    #pragma unroll
    for (int g2 = 0; g2 < 2; ++g2) {
        const int g = (2 * w + g2) * 16 + lr;
        const float bU = bu[g], bV = bv[g];
        #pragma unroll
        for (int r = 0; r < 4; ++r) {
            float Ux = accU[g2][0][r] + bU;
            float Uy = accU[g2][1][r] + bU;
            float Uz = accU[g2][2][r] + bU;
            float Vx = accV[g2][0][r] + bV;
            float Vy = accV[g2][1][r] + bV;
            float Vz = accV[g2][2][r] + bV;
            accU[g2][0][r] = Ux;
            accU[g2][1][r] = Uy;
            accU[g2][2][r] = Uz;
            uvr[g2][r] = Ux * Vx + Uy * Vy + Uz * Vz;
            float vn = sqrtf(Vx * Vx + Vy * Vy + Vz * Vz);
            int n = lq * 4 + r;
            int gr = 16 + (g >> 3);
            Hs[(n * 32 + (gr ^ n)) * 8 + (g & 7)] = (_Float16)vn;
        }
    }
    __syncthreads();

    // ---- GEMM2: h1 = silu(Wu1 @ [s;Vn] + bu1) (single 16-row tile) ----
    f4 acc2[2];
    acc2[0] = z4; acc2[1] = z4;
    {
        const _Float16* bb = Wu1h + (size_t)lr * 256 + lq * 8;
        #pragma unroll
        for (int g2 = 0; g2 < 2; ++g2) {
            h8 bfr[8];
            #pragma unroll
            for (int ks = 0; ks < 8; ++ks)
                bfr[ks] = *(const h8*)(bb + ((2 * w + g2) * 16) * 256 + ks * 32);
            #pragma unroll
            for (int ks = 0; ks < 8; ++ks) {
                h8 af = *(const h8*)&Hs[(lr * 32 + ((ks * 4 + lq) ^ lr)) * 8];
                acc2[g2] = __builtin_amdgcn_mfma_f32_16x16x32_f16(
                    af, bfr[ks], acc2[g2], 0, 0, 0);
            }
        }
    }
    #pragma unroll
    for (int g2 = 0; g2 < 2; ++g2) {
        const int g = (2 * w + g2) * 16 + lr;
        const float b1 = bu1[g];
        #pragma unroll
        for (int r = 0; r < 4; ++r) {
            float x = acc2[g2][r] + b1;
            float y = x / (1.f + __expf(-x));
            int n = lq * 4 + r;
            H1s[(n * 16 + ((g >> 3) ^ n)) * 8 + (g & 7)] = (_Float16)y;
        }
    }
    __syncthreads();

    // ---- GEMM3: a = Wu2 @ h1 + bu2 (single 16-row tile) ----
    f4 acc3[3][2];
    #pragma unroll
    for (int a = 0; a < 3; ++a) { acc3[a][0] = z4; acc3[a][1] = z4; }
    {
        const _Float16* bb = Wu2h + (size_t)lr * 128 + lq * 8;
        #pragma unroll
        for (int ai = 0; ai < 3; ++ai)
            #pragma unroll
            for (int g2 = 0; g2 < 2; ++g2) {
                const int jt = ai * 8 + 2 * w + g2;
                h8 bfr[4];
                #pragma unroll
                for (int ks = 0; ks < 4; ++ks)
                    bfr[ks] = *(const h8*)(bb + (size_t)(jt * 16) * 128 + ks * 32);
                #pragma unroll
                for (int ks = 0; ks < 4; ++ks) {
                    h8 af = *(const h8*)&H1s[(lr * 16 + ((ks * 4 + lq) ^ lr)) * 8];
                    acc3[ai][g2] = __builtin_amdgcn_mfma_f32_16x16x32_f16(
                        af, bfr[ks], acc3[ai][g2], 0, 0, 0);
                }
            }
    }

    // ---- final epilogue: residuals from staged f16 LDS tiles ----
    #pragma unroll
    for (int g2 = 0; g2 < 2; ++g2) {
        const int g = (2 * w + g2) * 16 + lr;
        const float b1 = bu2[g], b2 = bu2[128 + g], b3 = bu2[256 + g];
        #pragma unroll
        for (int r = 0; r < 4; ++r) {
            int n = lq * 4 + r;
            int nn = n0 + n;
            if (nn < NN) {
                float a1 = acc3[0][g2][r] + b1;
                float a2 = acc3[1][g2][r] + b2;
                float a3 = acc3[2][g2][r] + b3;
                size_t gi = (size_t)nn * FF + g;
                float s1 = (float)Hs[(n * 32 + ((g >> 3) ^ n)) * 8 + (g & 7)];
                s_io[gi] = s1 + a2 + uvr[g2][r] * a3;
                float vx = (float)Xs[((0 * 16 + n) * 16 + ((g >> 3) ^ n)) * 8 + (g & 7)];
                float vy = (float)Xs[((1 * 16 + n) * 16 + ((g >> 3) ^ n)) * 8 + (g & 7)];
                float vz = (float)Xs[((2 * 16 + n) * 16 + ((g >> 3) ^ n)) * 8 + (g & 7)];
                v_io[gi * 3 + 0] = vx + accU[g2][0][r] * a1;
                v_io[gi * 3 + 1] = vy + accU[g2][1][r] * a1;
                v_io[gi * 3 + 2] = vz + accU[g2][2][r] * a1;
            }
        }
    }
}

// ---------------------------------------------------------------------------
extern "C" void kernel_launch(void* const* d_in, const int* in_sizes, int n_in,
                              void* d_out, int out_size, void* d_ws, size_t ws_size,
                              hipStream_t stream)
{
    const float* pos = (const float*)d_in[0];
    const float* emb = (const float*)d_in[1];
    const float* Wp1 = (const float*)d_in[2];
    const float* bp1 = (const float*)d_in[3];
    const float* Wp2 = (const float*)d_in[4];
    const float* bp2 = (const float*)d_in[5];
    const float* Ww  = (const float*)d_in[6];
    const float* bw  = (const float*)d_in[7];
    const float* Wu  = (const float*)d_in[8];
    const float* bu  = (const float*)d_in[9];
    const float* Wv  = (const float*)d_in[10];
    const float* bv  = (const float*)d_in[11];
    const float* Wu1 = (const float*)d_in[12];
    const float* bu1 = (const float*)d_in[13];
    const float* Wu2 = (const float*)d_in[14];
    const float* bu2 = (const float*)d_in[15];
    const int* z   = (const int*)d_in[16];
    const int* src = (const int*)d_in[17];
    const int* dst = (const int*)d_in[18];

    float* s_io = (float*)d_out;
    float* v_io = (float*)d_out + (size_t)NN * FF;

    char* ws = (char*)d_ws;
    unsigned int* phi_pk = (unsigned int*)ws;                 // NN*FF uints
    _Float16* xg    = (_Float16*)(phi_pk + (size_t)NN * FF);  // NN*3*FF
    _Float16* s_h   = xg + (size_t)NN * 3 * FF;               // NN*FF
    _Float16* Wuh   = s_h + (size_t)NN * FF;
    _Float16* Wvh   = Wuh  + 128 * 128;
    _Float16* Wu1h  = Wvh  + 128 * 128;
    _Float16* Wu2h  = Wu1h + 128 * 256;
    _Float16* Wp1h  = Wu2h + 384 * 128;
    _Float16* Wp2h  = Wp1h + 128 * 128;
    _Float16* Wwh32 = Wp2h + 384 * 128;                       // 256*32
    int* counts = (int*)(Wwh32 + 256 * 32);
    int* slots  = counts + NN;

    k_wconv <<<196, 256, 0, stream>>>(Wu, Wv, Wu1, Wu2, Wp1, Wp2, Ww, bw,
                                      Wuh, Wvh, Wu1h, Wu2h, Wp1h, Wp2h, Wwh32,
                                      counts);
    k_phi_bucket<<<(NN + 31) / 32, 256, 0, stream>>>(emb, z, Wp1h, bp1,
                                                     Wp2h, bp2, phi_pk, s_h,
                                                     dst, counts, slots);
    k_edge_mfma<<<NN, 128, 0, stream>>>(pos, Wwh32, src, counts, slots,
                                        phi_pk, s_h, xg);
    k_update_mfma<<<(NN + 15) / 16, 256, 0, stream>>>(xg, s_h,
                                                      Wuh, Wvh, Wu1h, Wu2h,
                                                      bu, bv, bu1, bu2,
                                                      s_io, v_io);
}